// Round 15
// baseline (436.643 us; speedup 1.0000x reference)
//
#include <hip/hip_runtime.h>

// SensorAutoEncoder: 10-layer MLP over 1M rows of 43 floats. fp16 MFMA
// (16x16x32) + fp32 accumulate. R15 = R13's structure (LDS = weights only,
// 64,000 B -> 2 blocks/CU; M=16/wave; register-resident F-permuted chain)
// with the x-phase made to GENUINELY fit the 64-VGPR target the compiler
// picks at this LDS size (R12-R14 spilled ~850 MB/dispatch because the
// 16-scalar-load + clamp-branch path exceeded 64 including loads-in-flight):
//   - x loaded as 4x dwordx4 (memcpy idiom, 32-bit offsets, saddr+voffset)
//   - no clamp branch: min() on the two high quad offsets + a lane-predicated
//     4-cndmask fixup for the single (row N-1, g==1) case; one code path.
//   B slot (c,g,j): c==0 -> F = 16*(j>>2) + 4g + (j&3)
//                   c==1, j<4 -> F = 32 + 4g + j ; else zero pad
// bias via k==KL row; forced 1.0 multiplier at slot (c1,g=1,j=3); junk
// k-slots annihilated by zero A rows; layer-9 overhang covered by zeroed pad.

typedef __fp16 pk16x2 __attribute__((ext_vector_type(2)));   // cvt_pkrtz type
typedef _Float16 f16x8 __attribute__((ext_vector_type(8)));
typedef float f32x4 __attribute__((ext_vector_type(4)));
typedef unsigned u32x4 __attribute__((ext_vector_type(4)));

#define TPB 1024
#define NBLK 512
#define ITERS 8
#define NROWS 1048576
#define NCOL 43
#define ROWB 172u                        // bytes per x / out row (43 f32)
#define XBYTES ((size_t)NROWS * ROWB)    // 180,355,072
#define WSTRIDE 72                       // halfwords per W^T row (144 B)
#define SLOT_ROWS 44
#define WSLOT (SLOT_ROWS * WSTRIDE)      // 3168 halfwords per layer slot
#define W_HW (10 * WSLOT)                // 31680 halfwords
#define W_PAD_HW 320                     // layer-9 overhang rows, zeroed
#define SMEM_BYTES ((W_HW + W_PAD_HW) * 2)  // 64000 B -> 2 blocks/CU
// rb of the one lane needing the tail fixup: row NROWS-1, g==1
#define FIXRB ((unsigned)((NROWS - 1) * (size_t)ROWB) + 32u)

__device__ __forceinline__ float fast_tanh(float x) {
  // tanh(x) = 1 - 2/(1 + e^{2x});  e^{2x} = 2^{x * 2*log2(e)}
  float t = __builtin_amdgcn_exp2f(x * 2.8853900817779268f);
  float r = __builtin_amdgcn_rcpf(t + 1.0f);
  return __builtin_fmaf(-2.0f, r, 1.0f);
}

__device__ __forceinline__ unsigned pk2(float a, float b) {
  pk16x2 h = __builtin_amdgcn_cvt_pkrtz(a, b);
  return __builtin_bit_cast(unsigned, h);
}

__device__ __forceinline__ f32x4 ld16(const char* p) {
  f32x4 v;
  __builtin_memcpy(&v, __builtin_assume_aligned(p, 4), 16);
  return v;
}

struct Frag2 { f16x8 c0, c1; };

// Build the layer-0 B-frag. rb = row*172 + 32g (dword-aligned). Quads q2/q3
// offset-clamped to XBYTES-16; only (row==N-1, g==1) has real k's (40..42) in
// a clamped quad — the clamped load holds them shifted by one dword; fixup.
__device__ __forceinline__ Frag2 build_b0(const char* __restrict__ xc,
                                          unsigned rb, int g) {
  const unsigned XL = (unsigned)(XBYTES - 16);
  unsigned o2 = rb + 128u; o2 = (o2 < XL) ? o2 : XL;
  unsigned o3 = rb + 144u; o3 = (o3 < XL) ? o3 : XL;
  f32x4 q0 = ld16(xc + rb);
  f32x4 q1 = ld16(xc + rb + 16u);
  f32x4 q2 = ld16(xc + o2);
  f32x4 q3 = ld16(xc + o3);
  if (rb == FIXRB) {                       // single lane chip-wide, per iter
    q2 = f32x4{q2[1], q2[2], q2[3], q2[3]};  // restore x[40..42]
  }
  float e3 = (g == 1) ? 1.0f : q2[3];      // k==43 bias multiplier := 1.0
  u32x4 d0 = {pk2(q0[0], q0[1]), pk2(q0[2], q0[3]),
              pk2(q1[0], q1[1]), pk2(q1[2], q1[3])};
  u32x4 d1 = {pk2(q2[0], q2[1]), pk2(q2[2], e3),
              pk2(q3[0], q3[1]), pk2(q3[2], q3[3])};
  Frag2 B;
  B.c0 = __builtin_bit_cast(f16x8, d0);
  B.c1 = __builtin_bit_cast(f16x8, d1);
  return B;
}

// One layer: JIT A-reads from LDS weights, MFMA (zero-C first chunk),
// epilogue (tanh + bias-column 1.0 forcing), pack into next B-frag.
template <int NT, int KC, bool DOTANH, int NLOUT, int KCN>
__device__ __forceinline__ Frag2 layer_fwd(const _Float16* __restrict__ Wl,
                                           Frag2 Bi, f32x4 Z, int g, int lr) {
  const _Float16* p = Wl + lr * WSTRIDE + 8 * g;
  f32x4 acc[3];
  acc[0] = __builtin_amdgcn_mfma_f32_16x16x32_f16(*(const f16x8*)(p),
                                                  Bi.c0, Z, 0, 0, 0);
  if constexpr (NT > 1)
    acc[1] = __builtin_amdgcn_mfma_f32_16x16x32_f16(
        *(const f16x8*)(p + 16 * WSTRIDE), Bi.c0, Z, 0, 0, 0);
  if constexpr (NT > 2)
    acc[2] = __builtin_amdgcn_mfma_f32_16x16x32_f16(
        *(const f16x8*)(p + 32 * WSTRIDE), Bi.c0, Z, 0, 0, 0);
  if constexpr (KC > 1) {
    acc[0] = __builtin_amdgcn_mfma_f32_16x16x32_f16(*(const f16x8*)(p + 32),
                                                    Bi.c1, acc[0], 0, 0, 0);
    if constexpr (NT > 1)
      acc[1] = __builtin_amdgcn_mfma_f32_16x16x32_f16(
          *(const f16x8*)(p + 16 * WSTRIDE + 32), Bi.c1, acc[1], 0, 0, 0);
    if constexpr (NT > 2)
      acc[2] = __builtin_amdgcn_mfma_f32_16x16x32_f16(
          *(const f16x8*)(p + 32 * WSTRIDE + 32), Bi.c1, acc[2], 0, 0, 0);
  }

  unsigned pk[3][2];
#pragma unroll
  for (int t = 0; t < NT; ++t) {
    float v[4];
#pragma unroll
    for (int r = 0; r < 4; ++r) {
      float u = acc[t][r];
      if (DOTANH) u = fast_tanh(u);
      if (t == (NLOUT >> 4)) {                 // bias-mult column -> 1.0
        int col = 16 * t + 4 * g + r;
        u = (col == NLOUT) ? 1.0f : u;
      }
      v[r] = u;
    }
    pk[t][0] = pk2(v[0], v[1]);
    pk[t][1] = pk2(v[2], v[3]);
  }
  Frag2 O;
  u32x4 d0 = {pk[0][0], pk[0][1], pk[1][0], pk[1][1]};
  O.c0 = __builtin_bit_cast(f16x8, d0);
  if (KCN == 2) {
    u32x4 d1 = {pk[NT - 1][0], pk[NT - 1][1], 0u, 0u};
    O.c1 = __builtin_bit_cast(f16x8, d1);
  } else {
    O.c1 = O.c0;   // unused by a KC=1 consumer
  }
  return O;
}

extern "C" __global__ void __launch_bounds__(TPB)
ae_kernel(const float* __restrict__ x,
          const float* __restrict__ W0, const float* __restrict__ B0,
          const float* __restrict__ W1, const float* __restrict__ B1,
          const float* __restrict__ W2, const float* __restrict__ B2,
          const float* __restrict__ W3, const float* __restrict__ B3,
          const float* __restrict__ W4, const float* __restrict__ B4,
          const float* __restrict__ W5, const float* __restrict__ B5,
          const float* __restrict__ W6, const float* __restrict__ B6,
          const float* __restrict__ W7, const float* __restrict__ B7,
          const float* __restrict__ W8, const float* __restrict__ B8,
          const float* __restrict__ W9, const float* __restrict__ B9,
          float* __restrict__ out) {
  extern __shared__ char smem[];
  _Float16* lw = (_Float16*)smem;

  const int tid = threadIdx.x;
  const int wave = tid >> 6;
  const int lane = tid & 63;
  const int g = lane >> 4;
  const int lr = lane & 15;

  // ---- stage weights as fp16 W^T (k-permutation F for layers 1..9), bias
  //      at the slot mapping to k==KL; 44 rows per slot; zero the pad ----
  {
    const float* Wp[10] = {W0, W1, W2, W3, W4, W5, W6, W7, W8, W9};
    const float* Bp[10] = {B0, B1, B2, B3, B4, B5, B6, B7, B8, B9};
    const int KLs[10] = {43, 43, 43, 43, 43, 21, 43, 43, 43, 43};
    const int NLs[10] = {43, 43, 43, 43, 21, 43, 43, 43, 43, 43};
#pragma unroll
    for (int L = 0; L < 10; ++L) {
      const float* Wl = Wp[L];
      const float* Bl = Bp[L];
      const int KL = KLs[L], NL = NLs[L];
      for (int idx = tid; idx < SLOT_ROWS * 64; idx += TPB) {
        int n = idx >> 6, kp = idx & 63;
        float v = 0.0f;
        if (n < NL) {
          int c = kp >> 5, g2 = (kp >> 3) & 3, j = kp & 7;
          int F;
          if (L == 0) F = kp;                               // natural
          else if (c == 0) F = 16 * (j >> 2) + 4 * g2 + (j & 3);
          else if (j < 4)  F = 32 + 4 * g2 + j;             // t=2 half
          else             F = 63;                          // zero pad slot
          if (F < KL) v = Wl[F * NL + n];                   // W^T: W[F][n]
          else if (F == KL) v = Bl[n];                      // bias row
        }
        lw[L * WSLOT + n * WSTRIDE + kp] = (_Float16)v;
      }
    }
    if (tid < W_PAD_HW) lw[W_HW + tid] = (_Float16)0.0f;
  }

  __syncthreads();  // weights ready; only barrier in the kernel

  const char* xc = (const char*)x;
  const unsigned blockbase = (unsigned)blockIdx.x * (ITERS * 256) + wave * 16;
  const f32x4 Z = {0.f, 0.f, 0.f, 0.f};   // shared MFMA C-init block

#pragma unroll 1
  for (int it = 0; it < ITERS; ++it) {
    const unsigned row0 = blockbase + (unsigned)it * 256u;
    const unsigned rb = (row0 + lr) * ROWB + 32u * g;

    // ---- layer-0 B-frag (single path for ALL blocks) ----
    Frag2 B = build_b0(xc, rb, g);

    // ---- layers 0..8, hidden state entirely in registers ----
    B = layer_fwd<3, 2, true, 43, 2>(lw + 0 * WSLOT, B, Z, g, lr);
    B = layer_fwd<3, 2, true, 43, 2>(lw + 1 * WSLOT, B, Z, g, lr);
    B = layer_fwd<3, 2, true, 43, 2>(lw + 2 * WSLOT, B, Z, g, lr);
    B = layer_fwd<3, 2, true, 43, 2>(lw + 3 * WSLOT, B, Z, g, lr);
    B = layer_fwd<2, 2, false, 21, 1>(lw + 4 * WSLOT, B, Z, g, lr);
    B = layer_fwd<3, 1, true, 43, 2>(lw + 5 * WSLOT, B, Z, g, lr);
    B = layer_fwd<3, 2, true, 43, 2>(lw + 6 * WSLOT, B, Z, g, lr);
    B = layer_fwd<3, 2, true, 43, 2>(lw + 7 * WSLOT, B, Z, g, lr);
    B = layer_fwd<3, 2, true, 43, 2>(lw + 8 * WSLOT, B, Z, g, lr);

    // ---- layer 9: linear, store fp32 via 32-bit offset + immediates ----
    {
      const _Float16* p = lw + 9 * WSLOT + lr * WSTRIDE + 8 * g;
      f32x4 a9[3];
      a9[0] = __builtin_amdgcn_mfma_f32_16x16x32_f16(*(const f16x8*)(p),
                                                     B.c0, Z, 0, 0, 0);
      a9[1] = __builtin_amdgcn_mfma_f32_16x16x32_f16(
          *(const f16x8*)(p + 16 * WSTRIDE), B.c0, Z, 0, 0, 0);
      a9[2] = __builtin_amdgcn_mfma_f32_16x16x32_f16(
          *(const f16x8*)(p + 32 * WSTRIDE), B.c0, Z, 0, 0, 0);
      a9[0] = __builtin_amdgcn_mfma_f32_16x16x32_f16(*(const f16x8*)(p + 32),
                                                     B.c1, a9[0], 0, 0, 0);
      a9[1] = __builtin_amdgcn_mfma_f32_16x16x32_f16(
          *(const f16x8*)(p + 16 * WSTRIDE + 32), B.c1, a9[1], 0, 0, 0);
      a9[2] = __builtin_amdgcn_mfma_f32_16x16x32_f16(
          *(const f16x8*)(p + 32 * WSTRIDE + 32), B.c1, a9[2], 0, 0, 0);

      const unsigned ob = (row0 + lr) * ROWB + 16u * g;
#pragma unroll
      for (int t = 0; t < 3; ++t)
#pragma unroll
        for (int r = 0; r < 4; ++r) {
          // col = 16t + 4g + r < 43; t<2 always in range
          if (t < 2 || 4 * g + r < 11)
            *(float*)((char*)out + (ob + 64u * t + 4u * r)) = a9[t][r];
        }
    }
  }
}

extern "C" void kernel_launch(void* const* d_in, const int* in_sizes, int n_in,
                              void* d_out, int out_size, void* d_ws,
                              size_t ws_size, hipStream_t stream) {
  const float* x = (const float*)d_in[0];
  const float* W[10];
  const float* B[10];
  for (int i = 0; i < 10; ++i) {
    W[i] = (const float*)d_in[1 + 2 * i];
    B[i] = (const float*)d_in[2 + 2 * i];
  }
  (void)hipFuncSetAttribute(reinterpret_cast<const void*>(ae_kernel),
                            hipFuncAttributeMaxDynamicSharedMemorySize,
                            SMEM_BYTES);
  ae_kernel<<<dim3(NBLK), dim3(TPB), SMEM_BYTES, stream>>>(
      x, W[0], B[0], W[1], B[1], W[2], B[2], W[3], B[3], W[4], B[4],
      W[5], B[5], W[6], B[6], W[7], B[7], W[8], B[8], W[9], B[9],
      (float*)d_out);
}

// Round 16
// 172.389 us; speedup vs baseline: 2.5329x; 2.5329x over previous
//
#include <hip/hip_runtime.h>

// SensorAutoEncoder: 10-layer MLP over 1M rows of 43 floats. fp16 MFMA
// (16x16x32) + fp32 accumulate. R16 = R15 (LDS = weights only, 64,000 B ->
// 2 blocks/CU; M=16/wave; register-resident F-permuted chain; one-path
// dwordx4 x loads with offset-clamp + single-lane fixup) + sched_barrier(0)
// at every layer boundary. At 64 KB LDS the backend caps VGPRs at 64 (the
// LDS-permitted 8-waves/EU target); R12-R15 spilled because the scheduler
// hoisted multiple layers' A-fragment ds_reads (24 VGPRs/layer) across the
// straight-line layer chain. The barriers pin each layer's loads inside its
// region: peak live ~60 <= 64, no spill; 8-wave TLP hides the LDS latency.
//   B slot (c,g,j): c==0 -> F = 16*(j>>2) + 4g + (j&3)
//                   c==1, j<4 -> F = 32 + 4g + j ; else zero pad
// bias via k==KL row; forced 1.0 multiplier at slot (c1,g=1,j=3); junk
// k-slots annihilated by zero A rows; layer-9 overhang covered by zeroed pad.

typedef __fp16 pk16x2 __attribute__((ext_vector_type(2)));   // cvt_pkrtz type
typedef _Float16 f16x8 __attribute__((ext_vector_type(8)));
typedef float f32x4 __attribute__((ext_vector_type(4)));
typedef unsigned u32x4 __attribute__((ext_vector_type(4)));

#define TPB 1024
#define NBLK 512
#define ITERS 8
#define NROWS 1048576
#define NCOL 43
#define ROWB 172u                        // bytes per x / out row (43 f32)
#define XBYTES ((size_t)NROWS * ROWB)    // 180,355,072
#define WSTRIDE 72                       // halfwords per W^T row (144 B)
#define SLOT_ROWS 44
#define WSLOT (SLOT_ROWS * WSTRIDE)      // 3168 halfwords per layer slot
#define W_HW (10 * WSLOT)                // 31680 halfwords
#define W_PAD_HW 320                     // layer-9 overhang rows, zeroed
#define SMEM_BYTES ((W_HW + W_PAD_HW) * 2)  // 64000 B -> 2 blocks/CU
// rb of the one lane needing the tail fixup: row NROWS-1, g==1
#define FIXRB ((unsigned)((NROWS - 1) * (size_t)ROWB) + 32u)

#define SBAR() __builtin_amdgcn_sched_barrier(0)

__device__ __forceinline__ float fast_tanh(float x) {
  // tanh(x) = 1 - 2/(1 + e^{2x});  e^{2x} = 2^{x * 2*log2(e)}
  float t = __builtin_amdgcn_exp2f(x * 2.8853900817779268f);
  float r = __builtin_amdgcn_rcpf(t + 1.0f);
  return __builtin_fmaf(-2.0f, r, 1.0f);
}

__device__ __forceinline__ unsigned pk2(float a, float b) {
  pk16x2 h = __builtin_amdgcn_cvt_pkrtz(a, b);
  return __builtin_bit_cast(unsigned, h);
}

__device__ __forceinline__ f32x4 ld16(const char* p) {
  f32x4 v;
  __builtin_memcpy(&v, __builtin_assume_aligned(p, 4), 16);
  return v;
}

struct Frag2 { f16x8 c0, c1; };

// Build the layer-0 B-frag. rb = row*172 + 32g (dword-aligned). Quads q2/q3
// offset-clamped to XBYTES-16; only (row==N-1, g==1) has real k's (40..42) in
// a clamped quad — the clamped load holds them shifted by one dword; fixup.
__device__ __forceinline__ Frag2 build_b0(const char* __restrict__ xc,
                                          unsigned rb, int g) {
  const unsigned XL = (unsigned)(XBYTES - 16);
  unsigned o2 = rb + 128u; o2 = (o2 < XL) ? o2 : XL;
  unsigned o3 = rb + 144u; o3 = (o3 < XL) ? o3 : XL;
  f32x4 q0 = ld16(xc + rb);
  f32x4 q1 = ld16(xc + rb + 16u);
  f32x4 q2 = ld16(xc + o2);
  f32x4 q3 = ld16(xc + o3);
  if (rb == FIXRB) {                       // single lane chip-wide, per iter
    q2 = f32x4{q2[1], q2[2], q2[3], q2[3]};  // restore x[40..42]
  }
  float e3 = (g == 1) ? 1.0f : q2[3];      // k==43 bias multiplier := 1.0
  u32x4 d0 = {pk2(q0[0], q0[1]), pk2(q0[2], q0[3]),
              pk2(q1[0], q1[1]), pk2(q1[2], q1[3])};
  u32x4 d1 = {pk2(q2[0], q2[1]), pk2(q2[2], e3),
              pk2(q3[0], q3[1]), pk2(q3[2], q3[3])};
  Frag2 B;
  B.c0 = __builtin_bit_cast(f16x8, d0);
  B.c1 = __builtin_bit_cast(f16x8, d1);
  return B;
}

// One layer: JIT A-reads from LDS weights, MFMA (zero-C first chunk),
// epilogue (tanh + bias-column 1.0 forcing), pack into next B-frag.
template <int NT, int KC, bool DOTANH, int NLOUT, int KCN>
__device__ __forceinline__ Frag2 layer_fwd(const _Float16* __restrict__ Wl,
                                           Frag2 Bi, f32x4 Z, int g, int lr) {
  const _Float16* p = Wl + lr * WSTRIDE + 8 * g;
  f32x4 acc[3];
  acc[0] = __builtin_amdgcn_mfma_f32_16x16x32_f16(*(const f16x8*)(p),
                                                  Bi.c0, Z, 0, 0, 0);
  if constexpr (NT > 1)
    acc[1] = __builtin_amdgcn_mfma_f32_16x16x32_f16(
        *(const f16x8*)(p + 16 * WSTRIDE), Bi.c0, Z, 0, 0, 0);
  if constexpr (NT > 2)
    acc[2] = __builtin_amdgcn_mfma_f32_16x16x32_f16(
        *(const f16x8*)(p + 32 * WSTRIDE), Bi.c0, Z, 0, 0, 0);
  if constexpr (KC > 1) {
    acc[0] = __builtin_amdgcn_mfma_f32_16x16x32_f16(*(const f16x8*)(p + 32),
                                                    Bi.c1, acc[0], 0, 0, 0);
    if constexpr (NT > 1)
      acc[1] = __builtin_amdgcn_mfma_f32_16x16x32_f16(
          *(const f16x8*)(p + 16 * WSTRIDE + 32), Bi.c1, acc[1], 0, 0, 0);
    if constexpr (NT > 2)
      acc[2] = __builtin_amdgcn_mfma_f32_16x16x32_f16(
          *(const f16x8*)(p + 32 * WSTRIDE + 32), Bi.c1, acc[2], 0, 0, 0);
  }

  unsigned pk[3][2];
#pragma unroll
  for (int t = 0; t < NT; ++t) {
    float v[4];
#pragma unroll
    for (int r = 0; r < 4; ++r) {
      float u = acc[t][r];
      if (DOTANH) u = fast_tanh(u);
      if (t == (NLOUT >> 4)) {                 // bias-mult column -> 1.0
        int col = 16 * t + 4 * g + r;
        u = (col == NLOUT) ? 1.0f : u;
      }
      v[r] = u;
    }
    pk[t][0] = pk2(v[0], v[1]);
    pk[t][1] = pk2(v[2], v[3]);
  }
  Frag2 O;
  u32x4 d0 = {pk[0][0], pk[0][1], pk[1][0], pk[1][1]};
  O.c0 = __builtin_bit_cast(f16x8, d0);
  if (KCN == 2) {
    u32x4 d1 = {pk[NT - 1][0], pk[NT - 1][1], 0u, 0u};
    O.c1 = __builtin_bit_cast(f16x8, d1);
  } else {
    O.c1 = O.c0;   // unused by a KC=1 consumer
  }
  return O;
}

extern "C" __global__ void __launch_bounds__(TPB)
ae_kernel(const float* __restrict__ x,
          const float* __restrict__ W0, const float* __restrict__ B0,
          const float* __restrict__ W1, const float* __restrict__ B1,
          const float* __restrict__ W2, const float* __restrict__ B2,
          const float* __restrict__ W3, const float* __restrict__ B3,
          const float* __restrict__ W4, const float* __restrict__ B4,
          const float* __restrict__ W5, const float* __restrict__ B5,
          const float* __restrict__ W6, const float* __restrict__ B6,
          const float* __restrict__ W7, const float* __restrict__ B7,
          const float* __restrict__ W8, const float* __restrict__ B8,
          const float* __restrict__ W9, const float* __restrict__ B9,
          float* __restrict__ out) {
  extern __shared__ char smem[];
  _Float16* lw = (_Float16*)smem;

  const int tid = threadIdx.x;
  const int wave = tid >> 6;
  const int lane = tid & 63;
  const int g = lane >> 4;
  const int lr = lane & 15;

  // ---- stage weights as fp16 W^T (k-permutation F for layers 1..9), bias
  //      at the slot mapping to k==KL; 44 rows per slot; zero the pad ----
  {
    const float* Wp[10] = {W0, W1, W2, W3, W4, W5, W6, W7, W8, W9};
    const float* Bp[10] = {B0, B1, B2, B3, B4, B5, B6, B7, B8, B9};
    const int KLs[10] = {43, 43, 43, 43, 43, 21, 43, 43, 43, 43};
    const int NLs[10] = {43, 43, 43, 43, 21, 43, 43, 43, 43, 43};
#pragma unroll
    for (int L = 0; L < 10; ++L) {
      const float* Wl = Wp[L];
      const float* Bl = Bp[L];
      const int KL = KLs[L], NL = NLs[L];
      for (int idx = tid; idx < SLOT_ROWS * 64; idx += TPB) {
        int n = idx >> 6, kp = idx & 63;
        float v = 0.0f;
        if (n < NL) {
          int c = kp >> 5, g2 = (kp >> 3) & 3, j = kp & 7;
          int F;
          if (L == 0) F = kp;                               // natural
          else if (c == 0) F = 16 * (j >> 2) + 4 * g2 + (j & 3);
          else if (j < 4)  F = 32 + 4 * g2 + j;             // t=2 half
          else             F = 63;                          // zero pad slot
          if (F < KL) v = Wl[F * NL + n];                   // W^T: W[F][n]
          else if (F == KL) v = Bl[n];                      // bias row
        }
        lw[L * WSLOT + n * WSTRIDE + kp] = (_Float16)v;
      }
    }
    if (tid < W_PAD_HW) lw[W_HW + tid] = (_Float16)0.0f;
  }

  __syncthreads();  // weights ready; only barrier in the kernel

  const char* xc = (const char*)x;
  const unsigned blockbase = (unsigned)blockIdx.x * (ITERS * 256) + wave * 16;
  const f32x4 Z = {0.f, 0.f, 0.f, 0.f};   // shared MFMA C-init block

#pragma unroll 1
  for (int it = 0; it < ITERS; ++it) {
    const unsigned row0 = blockbase + (unsigned)it * 256u;
    const unsigned rb = (row0 + lr) * ROWB + 32u * g;

    // ---- layer-0 B-frag (single path for ALL blocks) ----
    Frag2 B = build_b0(xc, rb, g);
    SBAR();

    // ---- layers 0..8; sched_barrier pins each layer's ds_reads inside
    //      its own region (keeps peak VGPR demand under the 64 cap) ----
    B = layer_fwd<3, 2, true, 43, 2>(lw + 0 * WSLOT, B, Z, g, lr);  SBAR();
    B = layer_fwd<3, 2, true, 43, 2>(lw + 1 * WSLOT, B, Z, g, lr);  SBAR();
    B = layer_fwd<3, 2, true, 43, 2>(lw + 2 * WSLOT, B, Z, g, lr);  SBAR();
    B = layer_fwd<3, 2, true, 43, 2>(lw + 3 * WSLOT, B, Z, g, lr);  SBAR();
    B = layer_fwd<2, 2, false, 21, 1>(lw + 4 * WSLOT, B, Z, g, lr); SBAR();
    B = layer_fwd<3, 1, true, 43, 2>(lw + 5 * WSLOT, B, Z, g, lr);  SBAR();
    B = layer_fwd<3, 2, true, 43, 2>(lw + 6 * WSLOT, B, Z, g, lr);  SBAR();
    B = layer_fwd<3, 2, true, 43, 2>(lw + 7 * WSLOT, B, Z, g, lr);  SBAR();
    B = layer_fwd<3, 2, true, 43, 2>(lw + 8 * WSLOT, B, Z, g, lr);  SBAR();

    // ---- layer 9: linear, store fp32 via 32-bit offset + immediates ----
    {
      const _Float16* p = lw + 9 * WSLOT + lr * WSTRIDE + 8 * g;
      f32x4 a9[3];
      a9[0] = __builtin_amdgcn_mfma_f32_16x16x32_f16(*(const f16x8*)(p),
                                                     B.c0, Z, 0, 0, 0);
      a9[1] = __builtin_amdgcn_mfma_f32_16x16x32_f16(
          *(const f16x8*)(p + 16 * WSTRIDE), B.c0, Z, 0, 0, 0);
      a9[2] = __builtin_amdgcn_mfma_f32_16x16x32_f16(
          *(const f16x8*)(p + 32 * WSTRIDE), B.c0, Z, 0, 0, 0);
      a9[0] = __builtin_amdgcn_mfma_f32_16x16x32_f16(*(const f16x8*)(p + 32),
                                                     B.c1, a9[0], 0, 0, 0);
      a9[1] = __builtin_amdgcn_mfma_f32_16x16x32_f16(
          *(const f16x8*)(p + 16 * WSTRIDE + 32), B.c1, a9[1], 0, 0, 0);
      a9[2] = __builtin_amdgcn_mfma_f32_16x16x32_f16(
          *(const f16x8*)(p + 32 * WSTRIDE + 32), B.c1, a9[2], 0, 0, 0);
      SBAR();

      const unsigned ob = (row0 + lr) * ROWB + 16u * g;
#pragma unroll
      for (int t = 0; t < 3; ++t)
#pragma unroll
        for (int r = 0; r < 4; ++r) {
          // col = 16t + 4g + r < 43; t<2 always in range
          if (t < 2 || 4 * g + r < 11)
            *(float*)((char*)out + (ob + 64u * t + 4u * r)) = a9[t][r];
        }
    }
    SBAR();
  }
}

extern "C" void kernel_launch(void* const* d_in, const int* in_sizes, int n_in,
                              void* d_out, int out_size, void* d_ws,
                              size_t ws_size, hipStream_t stream) {
  const float* x = (const float*)d_in[0];
  const float* W[10];
  const float* B[10];
  for (int i = 0; i < 10; ++i) {
    W[i] = (const float*)d_in[1 + 2 * i];
    B[i] = (const float*)d_in[2 + 2 * i];
  }
  (void)hipFuncSetAttribute(reinterpret_cast<const void*>(ae_kernel),
                            hipFuncAttributeMaxDynamicSharedMemorySize,
                            SMEM_BYTES);
  ae_kernel<<<dim3(NBLK), dim3(TPB), SMEM_BYTES, stream>>>(
      x, W[0], B[0], W[1], B[1], W[2], B[2], W[3], B[3], W[4], B[4],
      W[5], B[5], W[6], B[6], W[7], B[7], W[8], B[8], W[9], B[9],
      (float*)d_out);
}

// Round 17
// 168.157 us; speedup vs baseline: 2.5966x; 1.0252x over previous
//
#include <hip/hip_runtime.h>

// SensorAutoEncoder: 10-layer MLP over 1M rows of 43 floats. fp16 MFMA
// (16x16x32) + fp32 accumulate. R17 = synthesis of the measured constraints:
//   - M=32 rows/wave (s=0,1): A-fragment ds_reads amortize over 2x rows ->
//     LDS pipe ~50 us/CU (R16's M=16 doubled LDS traffic to ~96 us/CU)
//   - LDS = weights only (64,000 B) -> exactly 2 blocks/CU x 256 CU = 512
//     blocks co-resident -> 8 waves/SIMD (R16-proven occupancy ~60%)
//   - sched_barrier(0) at layer boundaries (R16-proven): pins each layer's
//     ds_reads in-region so peak VGPR demand stays under the 64-VGPR cap
//     the backend imposes at this LDS size (no spill; R12-R15's failure)
//   B slot (c,g,j): c==0 -> F = 16*(j>>2) + 4g + (j&3)
//                   c==1, j<4 -> F = 32 + 4g + j ; else zero pad
// k-permutation F folded into weight staging; bias via k==KL row; forced 1.0
// multiplier at slot (c1,g=1,j=3); junk k-slots annihilated by zero A rows;
// layer-9 A-read overhang covered by zeroed pad.

typedef __fp16 pk16x2 __attribute__((ext_vector_type(2)));   // cvt_pkrtz type
typedef _Float16 f16x8 __attribute__((ext_vector_type(8)));
typedef float f32x4 __attribute__((ext_vector_type(4)));
typedef unsigned u32x4 __attribute__((ext_vector_type(4)));

#define TPB 1024
#define NBLK 512
#define ITERS 4
#define NROWS 1048576
#define NCOL 43
#define ROWB 172u                        // bytes per x / out row (43 f32)
#define XBYTES ((size_t)NROWS * ROWB)    // 180,355,072
#define WSTRIDE 72                       // halfwords per W^T row (144 B)
#define SLOT_ROWS 44
#define WSLOT (SLOT_ROWS * WSTRIDE)      // 3168 halfwords per layer slot
#define W_HW (10 * WSLOT)                // 31680 halfwords
#define W_PAD_HW 320                     // layer-9 overhang rows, zeroed
#define SMEM_BYTES ((W_HW + W_PAD_HW) * 2)  // 64000 B -> 2 blocks/CU
// rb of the one lane needing the tail fixup: row NROWS-1, g==1
#define FIXRB ((unsigned)((NROWS - 1) * (size_t)ROWB) + 32u)

#define SBAR() __builtin_amdgcn_sched_barrier(0)

__device__ __forceinline__ float fast_tanh(float x) {
  // tanh(x) = 1 - 2/(1 + e^{2x});  e^{2x} = 2^{x * 2*log2(e)}
  float t = __builtin_amdgcn_exp2f(x * 2.8853900817779268f);
  float r = __builtin_amdgcn_rcpf(t + 1.0f);
  return __builtin_fmaf(-2.0f, r, 1.0f);
}

__device__ __forceinline__ unsigned pk2(float a, float b) {
  pk16x2 h = __builtin_amdgcn_cvt_pkrtz(a, b);
  return __builtin_bit_cast(unsigned, h);
}

__device__ __forceinline__ f32x4 ld16(const char* p) {
  f32x4 v;
  __builtin_memcpy(&v, __builtin_assume_aligned(p, 4), 16);
  return v;
}

struct Frag2 { f16x8 c0, c1; };
struct FragsV { f16x8 s0c0, s0c1, s1c0, s1c1; };

// Build one row's layer-0 B-frag. rb = row*172 + 32g (dword-aligned). Quads
// q2/q3 offset-clamped to XBYTES-16; only (row==N-1, g==1) has real k's
// (40..42) in a clamped quad — shifted by one dword there; fix up that lane.
__device__ __forceinline__ Frag2 build_b0(const char* __restrict__ xc,
                                          unsigned rb, int g) {
  const unsigned XL = (unsigned)(XBYTES - 16);
  unsigned o2 = rb + 128u; o2 = (o2 < XL) ? o2 : XL;
  unsigned o3 = rb + 144u; o3 = (o3 < XL) ? o3 : XL;
  f32x4 q0 = ld16(xc + rb);
  f32x4 q1 = ld16(xc + rb + 16u);
  f32x4 q2 = ld16(xc + o2);
  f32x4 q3 = ld16(xc + o3);
  if (rb == FIXRB) {                       // single lane chip-wide, per iter
    q2 = f32x4{q2[1], q2[2], q2[3], q2[3]};  // restore x[40..42]
  }
  float e3 = (g == 1) ? 1.0f : q2[3];      // k==43 bias multiplier := 1.0
  u32x4 d0 = {pk2(q0[0], q0[1]), pk2(q0[2], q0[3]),
              pk2(q1[0], q1[1]), pk2(q1[2], q1[3])};
  u32x4 d1 = {pk2(q2[0], q2[1]), pk2(q2[2], e3),
              pk2(q3[0], q3[1]), pk2(q3[2], q3[3])};
  Frag2 B;
  B.c0 = __builtin_bit_cast(f16x8, d0);
  B.c1 = __builtin_bit_cast(f16x8, d1);
  return B;
}

// One layer, M=32 (s=0,1): JIT A-reads (shared across s), MFMA (zero-C first
// chunk), epilogue (tanh + bias-column 1.0), pack into next B-frags.
template <int NT, int KC, bool DOTANH, int NLOUT, int KCN>
__device__ __forceinline__ FragsV layer_fwd(const _Float16* __restrict__ Wl,
                                            FragsV Bi, f32x4 Z, int g, int lr) {
  f16x8 Bv0[2] = {Bi.s0c0, Bi.s1c0};
  f16x8 Bv1[2] = {Bi.s0c1, Bi.s1c1};
  const _Float16* p = Wl + lr * WSTRIDE + 8 * g;

  f32x4 acc[3][2];
#pragma unroll
  for (int t = 0; t < NT; ++t) {
    f16x8 A = *(const f16x8*)(p + 16 * t * WSTRIDE);
#pragma unroll
    for (int s = 0; s < 2; ++s)
      acc[t][s] = __builtin_amdgcn_mfma_f32_16x16x32_f16(A, Bv0[s], Z, 0, 0, 0);
  }
  if constexpr (KC > 1) {
#pragma unroll
    for (int t = 0; t < NT; ++t) {
      f16x8 A = *(const f16x8*)(p + 16 * t * WSTRIDE + 32);
#pragma unroll
      for (int s = 0; s < 2; ++s)
        acc[t][s] = __builtin_amdgcn_mfma_f32_16x16x32_f16(A, Bv1[s],
                                                           acc[t][s], 0, 0, 0);
    }
  }

  f16x8 oc0[2], oc1[2];
#pragma unroll
  for (int s = 0; s < 2; ++s) {
    unsigned pk[3][2];
#pragma unroll
    for (int t = 0; t < NT; ++t) {
      float v[4];
#pragma unroll
      for (int r = 0; r < 4; ++r) {
        float u = acc[t][s][r];
        if (DOTANH) u = fast_tanh(u);
        if (t == (NLOUT >> 4)) {                 // bias-mult column -> 1.0
          int col = 16 * t + 4 * g + r;
          u = (col == NLOUT) ? 1.0f : u;
        }
        v[r] = u;
      }
      pk[t][0] = pk2(v[0], v[1]);
      pk[t][1] = pk2(v[2], v[3]);
    }
    u32x4 d0 = {pk[0][0], pk[0][1], pk[1][0], pk[1][1]};
    oc0[s] = __builtin_bit_cast(f16x8, d0);
    if (KCN == 2) {
      u32x4 d1 = {pk[NT - 1][0], pk[NT - 1][1], 0u, 0u};
      oc1[s] = __builtin_bit_cast(f16x8, d1);
    } else {
      oc1[s] = oc0[s];   // unused by a KC=1 consumer
    }
  }
  FragsV O;
  O.s0c0 = oc0[0]; O.s0c1 = oc1[0];
  O.s1c0 = oc0[1]; O.s1c1 = oc1[1];
  return O;
}

extern "C" __global__ void __launch_bounds__(TPB)
ae_kernel(const float* __restrict__ x,
          const float* __restrict__ W0, const float* __restrict__ B0,
          const float* __restrict__ W1, const float* __restrict__ B1,
          const float* __restrict__ W2, const float* __restrict__ B2,
          const float* __restrict__ W3, const float* __restrict__ B3,
          const float* __restrict__ W4, const float* __restrict__ B4,
          const float* __restrict__ W5, const float* __restrict__ B5,
          const float* __restrict__ W6, const float* __restrict__ B6,
          const float* __restrict__ W7, const float* __restrict__ B7,
          const float* __restrict__ W8, const float* __restrict__ B8,
          const float* __restrict__ W9, const float* __restrict__ B9,
          float* __restrict__ out) {
  extern __shared__ char smem[];
  _Float16* lw = (_Float16*)smem;

  const int tid = threadIdx.x;
  const int wave = tid >> 6;
  const int lane = tid & 63;
  const int g = lane >> 4;
  const int lr = lane & 15;

  // ---- stage weights as fp16 W^T (k-permutation F for layers 1..9), bias
  //      at the slot mapping to k==KL; 44 rows per slot; zero the pad ----
  {
    const float* Wp[10] = {W0, W1, W2, W3, W4, W5, W6, W7, W8, W9};
    const float* Bp[10] = {B0, B1, B2, B3, B4, B5, B6, B7, B8, B9};
    const int KLs[10] = {43, 43, 43, 43, 43, 21, 43, 43, 43, 43};
    const int NLs[10] = {43, 43, 43, 43, 21, 43, 43, 43, 43, 43};
#pragma unroll
    for (int L = 0; L < 10; ++L) {
      const float* Wl = Wp[L];
      const float* Bl = Bp[L];
      const int KL = KLs[L], NL = NLs[L];
      for (int idx = tid; idx < SLOT_ROWS * 64; idx += TPB) {
        int n = idx >> 6, kp = idx & 63;
        float v = 0.0f;
        if (n < NL) {
          int c = kp >> 5, g2 = (kp >> 3) & 3, j = kp & 7;
          int F;
          if (L == 0) F = kp;                               // natural
          else if (c == 0) F = 16 * (j >> 2) + 4 * g2 + (j & 3);
          else if (j < 4)  F = 32 + 4 * g2 + j;             // t=2 half
          else             F = 63;                          // zero pad slot
          if (F < KL) v = Wl[F * NL + n];                   // W^T: W[F][n]
          else if (F == KL) v = Bl[n];                      // bias row
        }
        lw[L * WSLOT + n * WSTRIDE + kp] = (_Float16)v;
      }
    }
    if (tid < W_PAD_HW) lw[W_HW + tid] = (_Float16)0.0f;
  }

  __syncthreads();  // weights ready; only barrier in the kernel

  const char* xc = (const char*)x;
  const unsigned blockbase = (unsigned)blockIdx.x * (ITERS * 512) + wave * 32;
  const f32x4 Z = {0.f, 0.f, 0.f, 0.f};   // shared MFMA C-init block

#pragma unroll 1
  for (int it = 0; it < ITERS; ++it) {
    const unsigned row0 = blockbase + (unsigned)it * 512u;

    // ---- layer-0 B-frags, s=0 then s=1 (SBAR bounds loads in flight) ----
    FragsV B;
    {
      Frag2 f0 = build_b0(xc, (row0 + lr) * ROWB + 32u * g, g);
      B.s0c0 = f0.c0; B.s0c1 = f0.c1;
    }
    SBAR();
    {
      Frag2 f1 = build_b0(xc, (row0 + 16u + lr) * ROWB + 32u * g, g);
      B.s1c0 = f1.c0; B.s1c1 = f1.c1;
    }
    SBAR();

    // ---- layers 0..8; sched_barrier pins each layer's ds_reads ----
    B = layer_fwd<3, 2, true, 43, 2>(lw + 0 * WSLOT, B, Z, g, lr);  SBAR();
    B = layer_fwd<3, 2, true, 43, 2>(lw + 1 * WSLOT, B, Z, g, lr);  SBAR();
    B = layer_fwd<3, 2, true, 43, 2>(lw + 2 * WSLOT, B, Z, g, lr);  SBAR();
    B = layer_fwd<3, 2, true, 43, 2>(lw + 3 * WSLOT, B, Z, g, lr);  SBAR();
    B = layer_fwd<2, 2, false, 21, 1>(lw + 4 * WSLOT, B, Z, g, lr); SBAR();
    B = layer_fwd<3, 1, true, 43, 2>(lw + 5 * WSLOT, B, Z, g, lr);  SBAR();
    B = layer_fwd<3, 2, true, 43, 2>(lw + 6 * WSLOT, B, Z, g, lr);  SBAR();
    B = layer_fwd<3, 2, true, 43, 2>(lw + 7 * WSLOT, B, Z, g, lr);  SBAR();
    B = layer_fwd<3, 2, true, 43, 2>(lw + 8 * WSLOT, B, Z, g, lr);  SBAR();

    // ---- layer 9: linear, A shared across s, stores via immediates ----
    {
      f16x8 Bv0[2] = {B.s0c0, B.s1c0};
      f16x8 Bv1[2] = {B.s0c1, B.s1c1};
      const _Float16* p = lw + 9 * WSLOT + lr * WSTRIDE + 8 * g;
      f32x4 a9[3][2];
#pragma unroll
      for (int t = 0; t < 3; ++t) {
        f16x8 A = *(const f16x8*)(p + 16 * t * WSTRIDE);
#pragma unroll
        for (int s = 0; s < 2; ++s)
          a9[t][s] = __builtin_amdgcn_mfma_f32_16x16x32_f16(A, Bv0[s], Z,
                                                            0, 0, 0);
      }
#pragma unroll
      for (int t = 0; t < 3; ++t) {
        f16x8 A = *(const f16x8*)(p + 16 * t * WSTRIDE + 32);
#pragma unroll
        for (int s = 0; s < 2; ++s)
          a9[t][s] = __builtin_amdgcn_mfma_f32_16x16x32_f16(A, Bv1[s],
                                                            a9[t][s], 0, 0, 0);
      }
      SBAR();
#pragma unroll
      for (int s = 0; s < 2; ++s) {
        const unsigned ob = (row0 + 16u * s + lr) * ROWB + 16u * g;
#pragma unroll
        for (int t = 0; t < 3; ++t)
#pragma unroll
          for (int r = 0; r < 4; ++r) {
            // col = 16t + 4g + r < 43; t<2 always in range
            if (t < 2 || 4 * g + r < 11)
              *(float*)((char*)out + (ob + 64u * t + 4u * r)) = a9[t][s][r];
          }
      }
    }
    SBAR();
  }
}

extern "C" void kernel_launch(void* const* d_in, const int* in_sizes, int n_in,
                              void* d_out, int out_size, void* d_ws,
                              size_t ws_size, hipStream_t stream) {
  const float* x = (const float*)d_in[0];
  const float* W[10];
  const float* B[10];
  for (int i = 0; i < 10; ++i) {
    W[i] = (const float*)d_in[1 + 2 * i];
    B[i] = (const float*)d_in[2 + 2 * i];
  }
  (void)hipFuncSetAttribute(reinterpret_cast<const void*>(ae_kernel),
                            hipFuncAttributeMaxDynamicSharedMemorySize,
                            SMEM_BYTES);
  ae_kernel<<<dim3(NBLK), dim3(TPB), SMEM_BYTES, stream>>>(
      x, W[0], B[0], W[1], B[1], W[2], B[2], W[3], B[3], W[4], B[4],
      W[5], B[5], W[6], B[6], W[7], B[7], W[8], B[8], W[9], B[9],
      (float*)d_out);
}